// Round 1
// baseline (400.153 us; speedup 1.0000x reference)
//
#include <hip/hip_runtime.h>
#include <hip/hip_bf16.h>

#define NN 2000      // nodes
#define NE 40000     // edges
#define NB 4         // batch
#define T_IN 34
#define TP 32        // output time steps
#define NC 32        // channels (C_IN == DC == 32)
#define NPOS (NB * TP * NN)   // 256000 positions

// ws layout (in floats):
//  deg:      [0, 2048)
//  dis:      [2048, 4096)
//  counts:   [4096, 6144)      (int)
//  offsets:  [6144, 8192)      (int, 2001 used)
//  cursor:   [8192, 10240)     (int)
//  csr_src:  [10240, 51200)    (int, 40000 used)
//  csr_norm: [51200, 92160)    (float, 40000 used)
//  hw:       [92160, 92160 + 8192000)
// total ~33.1 MB

__global__ __launch_bounds__(256) void zero_kernel(float* ws) {
    int i = blockIdx.x * 256 + threadIdx.x;
    if (i < 6144) ws[i] = 0.0f;   // deg, dis(harmless), counts
}

__global__ __launch_bounds__(256) void deg_count_kernel(
        const int* __restrict__ col, const float* __restrict__ ew,
        float* __restrict__ deg, int* __restrict__ counts) {
    int e = blockIdx.x * 256 + threadIdx.x;
    if (e >= NE) return;
    int c = col[e];
    atomicAdd(&deg[c], ew[e]);
    atomicAdd(&counts[c], 1);
}

__global__ __launch_bounds__(256) void scan_kernel(
        const float* __restrict__ deg, float* __restrict__ dis,
        const int* __restrict__ counts, int* __restrict__ offsets,
        int* __restrict__ cursor) {
    __shared__ int svals[2048];
    __shared__ int pa[256], pb[256];
    int t = threadIdx.x;
    for (int i = t; i < 2048; i += 256) svals[i] = (i < NN) ? counts[i] : 0;
    __syncthreads();
    int base = t * 8;
    int local[8];
    int s = 0;
#pragma unroll
    for (int j = 0; j < 8; ++j) { local[j] = s; s += svals[base + j]; }
    pa[t] = s;
    __syncthreads();
    int* psrc = pa; int* pdst = pb;
    for (int off = 1; off < 256; off <<= 1) {
        int v = psrc[t];
        if (t >= off) v += psrc[t - off];
        pdst[t] = v;
        __syncthreads();
        int* tmp = psrc; psrc = pdst; pdst = tmp;
    }
    int excl = psrc[t] - s;   // exclusive base for this thread's chunk
#pragma unroll
    for (int j = 0; j < 8; ++j) {
        int i = base + j;
        if (i < NN) { int o = excl + local[j]; offsets[i] = o; cursor[i] = o; }
    }
    if (t == 255) offsets[NN] = psrc[255];
    // dis = rsqrt(deg + 1)  (self-loop weight 1 -> deg always > 0)
    for (int i = t; i < NN; i += 256) dis[i] = rsqrtf(deg[i] + 1.0f);
}

__global__ __launch_bounds__(256) void csr_fill_kernel(
        const int* __restrict__ row, const int* __restrict__ col,
        const float* __restrict__ ew, const float* __restrict__ dis,
        int* __restrict__ cursor, int* __restrict__ csr_src,
        float* __restrict__ csr_norm) {
    int e = blockIdx.x * 256 + threadIdx.x;
    if (e >= NE) return;
    int r = row[e], c = col[e];
    int pos = atomicAdd(&cursor[c], 1);
    csr_src[pos] = r;
    csr_norm[pos] = dis[r] * ew[e] * dis[c];
}

// One thread per (b, t', n) position. Weights in LDS read at wave-uniform
// addresses (broadcast, conflict-free). x taps in registers. Fused:
// gates -> tanh*sigmoid -> gcn_w matmul -> hw.
__global__ __launch_bounds__(256) void conv_kernel(
        const float* __restrict__ x,
        const float* __restrict__ w1, const float* __restrict__ b1,
        const float* __restrict__ w2, const float* __restrict__ b2,
        const float* __restrict__ gw, float* __restrict__ hw) {
    __shared__ float4 sW[1024];   // [dc*32+c] = {w1a, w1b, w2a, w2b}
    __shared__ float sG[1024];    // gcn_w as-is: [dc*32+e]
    __shared__ float sB1[32], sB2[32];
    int tid = threadIdx.x;
    for (int i = tid; i < 1024; i += 256) {
        int dc = i >> 5, c = i & 31;
        sW[i] = make_float4(w1[dc * 64 + c * 2], w1[dc * 64 + c * 2 + 1],
                            w2[dc * 64 + c * 2], w2[dc * 64 + c * 2 + 1]);
        sG[i] = gw[i];
    }
    if (tid < 32) { sB1[tid] = b1[tid]; sB2[tid] = b2[tid]; }
    __syncthreads();

    int pos = blockIdx.x * 256 + tid;       // grid is exact: NPOS/256 blocks
    int bt = pos / 2000;
    int n = pos - bt * 2000;
    int b_ = bt >> 5;                        // TP == 32
    int t_ = bt & 31;
    const float* xa_p = x + (((b_ * T_IN + t_) * NN + n) << 5);
    const float* xb_p = xa_p + 2 * NN * NC;  // dilation 2 tap

    float xa[32], xb[32];
    const float4* xa4 = (const float4*)xa_p;
    const float4* xb4 = (const float4*)xb_p;
#pragma unroll
    for (int j = 0; j < 8; ++j) {
        float4 va = xa4[j], vb = xb4[j];
        xa[4 * j] = va.x; xa[4 * j + 1] = va.y; xa[4 * j + 2] = va.z; xa[4 * j + 3] = va.w;
        xb[4 * j] = vb.x; xb[4 * j + 1] = vb.y; xb[4 * j + 2] = vb.z; xb[4 * j + 3] = vb.w;
    }

    float acc[32];
#pragma unroll
    for (int e = 0; e < 32; ++e) acc[e] = 0.0f;

    const float4* sG4 = (const float4*)sG;
#pragma unroll 2
    for (int dc = 0; dc < 32; ++dc) {
        float g1 = sB1[dc], g2 = sB2[dc];
#pragma unroll
        for (int c = 0; c < 32; ++c) {
            float4 w = sW[dc * 32 + c];
            g1 += xa[c] * w.x + xb[c] * w.y;
            g2 += xa[c] * w.z + xb[c] * w.w;
        }
        float e2 = __expf(2.0f * g1);
        float th = (e2 - 1.0f) / (e2 + 1.0f);          // tanh(g1)
        float sg = 1.0f / (1.0f + __expf(-g2));        // sigmoid(g2)
        float hdc = th * sg;
#pragma unroll
        for (int j = 0; j < 8; ++j) {
            float4 gg = sG4[dc * 8 + j];
            acc[4 * j]     += hdc * gg.x;
            acc[4 * j + 1] += hdc * gg.y;
            acc[4 * j + 2] += hdc * gg.z;
            acc[4 * j + 3] += hdc * gg.w;
        }
    }

    float4* o4 = (float4*)(hw + (pos << 5));
#pragma unroll
    for (int j = 0; j < 8; ++j)
        o4[j] = make_float4(acc[4 * j], acc[4 * j + 1], acc[4 * j + 2], acc[4 * j + 3]);
}

// 32-lane unit per (bt, n): gather incoming messages from CSR.
__global__ __launch_bounds__(256) void agg_kernel(
        const float* __restrict__ hw, const int* __restrict__ offsets,
        const int* __restrict__ csr_src, const float* __restrict__ csr_norm,
        const float* __restrict__ dis, const float* __restrict__ gcb,
        float* __restrict__ out) {
    int u = blockIdx.x * 8 + (threadIdx.x >> 5);  // u = bt*2000 + n
    int c = threadIdx.x & 31;
    int bt = u / 2000;
    int n = u - bt * 2000;
    const float* hwb = hw + bt * (NN * NC);
    float dn = dis[n];
    float acc = hwb[(n << 5) + c] * (dn * dn);     // self loop
    int s = offsets[n], e = offsets[n + 1];
    for (int i = s; i < e; ++i) {
        int src = csr_src[i];
        float nr = csr_norm[i];
        acc += hwb[(src << 5) + c] * nr;
    }
    out[(u << 5) + c] = acc + gcb[c];
}

extern "C" void kernel_launch(void* const* d_in, const int* in_sizes, int n_in,
                              void* d_out, int out_size, void* d_ws, size_t ws_size,
                              hipStream_t stream) {
    const float* x   = (const float*)d_in[0];
    const int*   ei  = (const int*)d_in[1];
    const float* ew  = (const float*)d_in[2];
    const float* g1w = (const float*)d_in[3];
    const float* g1b = (const float*)d_in[4];
    const float* g2w = (const float*)d_in[5];
    const float* g2b = (const float*)d_in[6];
    const float* gcw = (const float*)d_in[7];
    const float* gcb = (const float*)d_in[8];
    float* out = (float*)d_out;

    float* wsf      = (float*)d_ws;
    float* deg      = wsf;
    float* dis      = wsf + 2048;
    int*   counts   = (int*)(wsf + 4096);
    int*   offsets  = (int*)(wsf + 6144);
    int*   cursor   = (int*)(wsf + 8192);
    int*   csr_src  = (int*)(wsf + 10240);
    float* csr_norm = wsf + 51200;
    float* hw       = wsf + 92160;

    const int* row = ei;
    const int* col = ei + NE;

    hipLaunchKernelGGL(zero_kernel, dim3(24), dim3(256), 0, stream, wsf);
    hipLaunchKernelGGL(deg_count_kernel, dim3((NE + 255) / 256), dim3(256), 0, stream,
                       col, ew, deg, counts);
    hipLaunchKernelGGL(scan_kernel, dim3(1), dim3(256), 0, stream,
                       deg, dis, counts, offsets, cursor);
    hipLaunchKernelGGL(csr_fill_kernel, dim3((NE + 255) / 256), dim3(256), 0, stream,
                       row, col, ew, dis, cursor, csr_src, csr_norm);
    hipLaunchKernelGGL(conv_kernel, dim3(NPOS / 256), dim3(256), 0, stream,
                       x, g1w, g1b, g2w, g2b, gcw, hw);
    hipLaunchKernelGGL(agg_kernel, dim3(NPOS / 8), dim3(256), 0, stream,
                       hw, offsets, csr_src, csr_norm, dis, gcb, out);
}

// Round 2
// 279.247 us; speedup vs baseline: 1.4330x; 1.4330x over previous
//
#include <hip/hip_runtime.h>
#include <hip/hip_bf16.h>

#define NN 2000      // nodes
#define NE 40000     // edges
#define NB 4         // batch
#define T_IN 34
#define TP 32        // output time steps
#define NC 32        // channels (C_IN == DC == 32)
#define NPOS (NB * TP * NN)   // 256000 positions
#define NBT (NB * TP)         // 128 bt slices

// ws layout (in floats):
//  deg:      [0, 2048)
//  dis:      [2048, 4096)
//  counts:   [4096, 6144)      (int)
//  offsets:  [6144, 8192)      (int, 2001 used)
//  cursor:   [8192, 10240)     (int)
//  csr_src:  [10240, 51200)    (int, 40000 used)
//  csr_norm: [51200, 92160)    (float, 40000 used)
//  hw:       [92160, 92160 + 8192000)

__global__ __launch_bounds__(256) void zero_kernel(float* ws) {
    int i = blockIdx.x * 256 + threadIdx.x;
    if (i < 6144) ws[i] = 0.0f;   // deg, dis(harmless), counts
}

__global__ __launch_bounds__(256) void deg_count_kernel(
        const int* __restrict__ col, const float* __restrict__ ew,
        float* __restrict__ deg, int* __restrict__ counts) {
    int e = blockIdx.x * 256 + threadIdx.x;
    if (e >= NE) return;
    int c = col[e];
    atomicAdd(&deg[c], ew[e]);
    atomicAdd(&counts[c], 1);
}

__global__ __launch_bounds__(256) void scan_kernel(
        const float* __restrict__ deg, float* __restrict__ dis,
        const int* __restrict__ counts, int* __restrict__ offsets,
        int* __restrict__ cursor) {
    __shared__ int svals[2048];
    __shared__ int pa[256], pb[256];
    int t = threadIdx.x;
    for (int i = t; i < 2048; i += 256) svals[i] = (i < NN) ? counts[i] : 0;
    __syncthreads();
    int base = t * 8;
    int local[8];
    int s = 0;
#pragma unroll
    for (int j = 0; j < 8; ++j) { local[j] = s; s += svals[base + j]; }
    pa[t] = s;
    __syncthreads();
    int* psrc = pa; int* pdst = pb;
    for (int off = 1; off < 256; off <<= 1) {
        int v = psrc[t];
        if (t >= off) v += psrc[t - off];
        pdst[t] = v;
        __syncthreads();
        int* tmp = psrc; psrc = pdst; pdst = tmp;
    }
    int excl = psrc[t] - s;   // exclusive base for this thread's chunk
#pragma unroll
    for (int j = 0; j < 8; ++j) {
        int i = base + j;
        if (i < NN) { int o = excl + local[j]; offsets[i] = o; cursor[i] = o; }
    }
    if (t == 255) offsets[NN] = psrc[255];
    for (int i = t; i < NN; i += 256) dis[i] = rsqrtf(deg[i] + 1.0f);
}

__global__ __launch_bounds__(256) void csr_fill_kernel(
        const int* __restrict__ row, const int* __restrict__ col,
        const float* __restrict__ ew, const float* __restrict__ dis,
        int* __restrict__ cursor, int* __restrict__ csr_src,
        float* __restrict__ csr_norm) {
    int e = blockIdx.x * 256 + threadIdx.x;
    if (e >= NE) return;
    int r = row[e], c = col[e];
    int pos = atomicAdd(&cursor[c], 1);
    csr_src[pos] = r;
    csr_norm[pos] = dis[r] * ew[e] * dis[c];
}

// One thread per (b, t', n). Weights read straight from global with
// wave-uniform indices -> compiler scalarizes to s_load through the
// constant cache (scalar pipe, no LDS contention). Gates use split
// accumulators to break the serial FMA chain.
__global__ __launch_bounds__(256) void conv_kernel(
        const float* __restrict__ x,
        const float* __restrict__ w1, const float* __restrict__ b1,
        const float* __restrict__ w2, const float* __restrict__ b2,
        const float* __restrict__ gw, float* __restrict__ hw) {
    int tid = threadIdx.x;
    int pos = blockIdx.x * 256 + tid;       // grid exact: NPOS/256
    int bt = pos / 2000;
    int n = pos - bt * 2000;
    int b_ = bt >> 5;                        // TP == 32
    int t_ = bt & 31;
    const float* xa_p = x + (((b_ * T_IN + t_) * NN + n) << 5);
    const float* xb_p = xa_p + 2 * NN * NC;  // dilation-2 tap

    float xa[32], xb[32];
    const float4* xa4 = (const float4*)xa_p;
    const float4* xb4 = (const float4*)xb_p;
#pragma unroll
    for (int j = 0; j < 8; ++j) {
        float4 va = xa4[j], vb = xb4[j];
        xa[4 * j] = va.x; xa[4 * j + 1] = va.y; xa[4 * j + 2] = va.z; xa[4 * j + 3] = va.w;
        xb[4 * j] = vb.x; xb[4 * j + 1] = vb.y; xb[4 * j + 2] = vb.z; xb[4 * j + 3] = vb.w;
    }

    float h[32];
#pragma unroll 8
    for (int dc = 0; dc < 32; ++dc) {
        const float* w1p = w1 + dc * 64;
        const float* w2p = w2 + dc * 64;
        float a0 = 0.f, a1 = 0.f, p0 = 0.f, p1 = 0.f;
#pragma unroll
        for (int c = 0; c < 32; c += 2) {
            a0 += xa[c]     * w1p[c * 2]     + xb[c]     * w1p[c * 2 + 1];
            a1 += xa[c + 1] * w1p[c * 2 + 2] + xb[c + 1] * w1p[c * 2 + 3];
            p0 += xa[c]     * w2p[c * 2]     + xb[c]     * w2p[c * 2 + 1];
            p1 += xa[c + 1] * w2p[c * 2 + 2] + xb[c + 1] * w2p[c * 2 + 3];
        }
        float g1 = b1[dc] + a0 + a1;
        float g2 = b2[dc] + p0 + p1;
        float e2 = __expf(2.0f * g1);
        float th = (e2 - 1.0f) / (e2 + 1.0f);          // tanh
        float sg = 1.0f / (1.0f + __expf(-g2));        // sigmoid
        h[dc] = th * sg;
    }

    float acc[32];
#pragma unroll
    for (int e = 0; e < 32; ++e) acc[e] = 0.0f;
#pragma unroll 8
    for (int dc = 0; dc < 32; ++dc) {
        const float* gp = gw + dc * 32;
        float hd = h[dc];
#pragma unroll
        for (int e = 0; e < 32; ++e) acc[e] += hd * gp[e];
    }

    float4* o4 = (float4*)(hw + (pos << 5));
#pragma unroll
    for (int j = 0; j < 8; ++j)
        o4[j] = make_float4(acc[4 * j], acc[4 * j + 1], acc[4 * j + 2], acc[4 * j + 3]);
}

// 32-lane unit per (node, bt-pair). Edge list loaded coalesced by the 32
// lanes, broadcast via width-32 shfl; gathers issued in bursts of 4 for
// two bt slices -> 8 independent loads in flight per burst.
__global__ __launch_bounds__(256) void agg_kernel(
        const float* __restrict__ hw, const int* __restrict__ offsets,
        const int* __restrict__ csr_src, const float* __restrict__ csr_norm,
        const float* __restrict__ dis, const float* __restrict__ gcb,
        float* __restrict__ out) {
    int u = blockIdx.x * 8 + (threadIdx.x >> 5);  // u in [0, 64*2000)
    int c = threadIdx.x & 31;
    int p = u / 2000;                // bt pair id [0,64)
    int n = u - p * 2000;
    int bt0 = p, bt1 = p + 64;
    const float* hwb0 = hw + bt0 * (NN * NC);
    const float* hwb1 = hw + bt1 * (NN * NC);
    float dn = dis[n];
    float dn2 = dn * dn;
    float acc0 = hwb0[(n << 5) + c] * dn2;   // self loop
    float acc1 = hwb1[(n << 5) + c] * dn2;
    int s = offsets[n], e = offsets[n + 1];

    for (int base = s; base < e; base += 32) {
        int cnt = e - base; if (cnt > 32) cnt = 32;
        int msrc = 0; float mnr = 0.0f;
        if (c < cnt) { msrc = csr_src[base + c]; mnr = csr_norm[base + c]; }
        int j = 0;
        for (; j + 4 <= cnt; j += 4) {
            int s0 = __shfl(msrc, j, 32),     s1 = __shfl(msrc, j + 1, 32);
            int s2 = __shfl(msrc, j + 2, 32), s3 = __shfl(msrc, j + 3, 32);
            float n0 = __shfl(mnr, j, 32),     n1 = __shfl(mnr, j + 1, 32);
            float n2 = __shfl(mnr, j + 2, 32), n3 = __shfl(mnr, j + 3, 32);
            int o0 = (s0 << 5) + c, o1 = (s1 << 5) + c;
            int o2 = (s2 << 5) + c, o3 = (s3 << 5) + c;
            float v0 = hwb0[o0], v1 = hwb0[o1], v2 = hwb0[o2], v3 = hwb0[o3];
            float u0 = hwb1[o0], u1 = hwb1[o1], u2 = hwb1[o2], u3 = hwb1[o3];
            acc0 += v0 * n0; acc0 += v1 * n1; acc0 += v2 * n2; acc0 += v3 * n3;
            acc1 += u0 * n0; acc1 += u1 * n1; acc1 += u2 * n2; acc1 += u3 * n3;
        }
        for (; j < cnt; ++j) {
            int sj = __shfl(msrc, j, 32);
            float nj = __shfl(mnr, j, 32);
            int oj = (sj << 5) + c;
            acc0 += hwb0[oj] * nj;
            acc1 += hwb1[oj] * nj;
        }
    }
    float bias = gcb[c];
    out[((bt0 * NN + n) << 5) + c] = acc0 + bias;
    out[((bt1 * NN + n) << 5) + c] = acc1 + bias;
}

extern "C" void kernel_launch(void* const* d_in, const int* in_sizes, int n_in,
                              void* d_out, int out_size, void* d_ws, size_t ws_size,
                              hipStream_t stream) {
    const float* x   = (const float*)d_in[0];
    const int*   ei  = (const int*)d_in[1];
    const float* ew  = (const float*)d_in[2];
    const float* g1w = (const float*)d_in[3];
    const float* g1b = (const float*)d_in[4];
    const float* g2w = (const float*)d_in[5];
    const float* g2b = (const float*)d_in[6];
    const float* gcw = (const float*)d_in[7];
    const float* gcb = (const float*)d_in[8];
    float* out = (float*)d_out;

    float* wsf      = (float*)d_ws;
    float* deg      = wsf;
    float* dis      = wsf + 2048;
    int*   counts   = (int*)(wsf + 4096);
    int*   offsets  = (int*)(wsf + 6144);
    int*   cursor   = (int*)(wsf + 8192);
    int*   csr_src  = (int*)(wsf + 10240);
    float* csr_norm = wsf + 51200;
    float* hw       = wsf + 92160;

    const int* row = ei;
    const int* col = ei + NE;

    hipLaunchKernelGGL(zero_kernel, dim3(24), dim3(256), 0, stream, wsf);
    hipLaunchKernelGGL(deg_count_kernel, dim3((NE + 255) / 256), dim3(256), 0, stream,
                       col, ew, deg, counts);
    hipLaunchKernelGGL(scan_kernel, dim3(1), dim3(256), 0, stream,
                       deg, dis, counts, offsets, cursor);
    hipLaunchKernelGGL(csr_fill_kernel, dim3((NE + 255) / 256), dim3(256), 0, stream,
                       row, col, ew, dis, cursor, csr_src, csr_norm);
    hipLaunchKernelGGL(conv_kernel, dim3(NPOS / 256), dim3(256), 0, stream,
                       x, g1w, g1b, g2w, g2b, gcw, hw);
    hipLaunchKernelGGL(agg_kernel, dim3(64 * 2000 / 8), dim3(256), 0, stream,
                       hw, offsets, csr_src, csr_norm, dis, gcb, out);
}

// Round 3
// 188.566 us; speedup vs baseline: 2.1221x; 1.4809x over previous
//
#include <hip/hip_runtime.h>
#include <hip/hip_bf16.h>

typedef short short8 __attribute__((ext_vector_type(8)));
typedef float floatx4 __attribute__((ext_vector_type(4)));

#define NN 2000      // nodes
#define NE 40000     // edges
#define NB 4         // batch
#define T_IN 34
#define TP 32        // output time steps
#define NBT (NB * TP)         // 128 bt slices
#define NPOS (NB * TP * NN)   // 256000 positions
#define NTILE (NPOS / 16)     // 16000 M-tiles (2000 % 16 == 0 -> tiles never cross bt)

// ws layout (floats):
//  deg[0,2048) dis[2048,4096) counts[4096,6144) offsets[6144,8192)
//  cursor[8192,10240) csr_src[10240,51200) csr_norm[51200,92160)
//  h2 (bf16 as ushort): [92160 .. 92160+4096000) floats  == 2000*128*32 ushorts
// total ~16.8 MB.  s lives in d_out (gcn applied in-place).

// ---------- bf16 helpers (RNE) ----------
__device__ inline unsigned short f2bf(float x) {
    unsigned int u = __float_as_uint(x);
    u = u + 0x7fff + ((u >> 16) & 1);
    return (unsigned short)(u >> 16);
}
__device__ inline float bf2f(unsigned short h) {
    return __uint_as_float(((unsigned int)h) << 16);
}
__device__ inline void split2(float x, unsigned short& hi, unsigned short& lo) {
    unsigned short h = f2bf(x);
    hi = h;
    lo = f2bf(x - bf2f(h));
}
__device__ inline void splitA(const float4& v0, const float4& v1, short8& hi, short8& lo) {
    float av[8] = {v0.x, v0.y, v0.z, v0.w, v1.x, v1.y, v1.z, v1.w};
#pragma unroll
    for (int j = 0; j < 8; ++j) {
        unsigned short h_, l_;
        split2(av[j], h_, l_);
        hi[j] = (short)h_; lo[j] = (short)l_;
    }
}

// ---------- graph prep (unchanged) ----------
__global__ __launch_bounds__(256) void zero_kernel(float* ws) {
    int i = blockIdx.x * 256 + threadIdx.x;
    if (i < 6144) ws[i] = 0.0f;
}

__global__ __launch_bounds__(256) void deg_count_kernel(
        const int* __restrict__ col, const float* __restrict__ ew,
        float* __restrict__ deg, int* __restrict__ counts) {
    int e = blockIdx.x * 256 + threadIdx.x;
    if (e >= NE) return;
    int c = col[e];
    atomicAdd(&deg[c], ew[e]);
    atomicAdd(&counts[c], 1);
}

__global__ __launch_bounds__(256) void scan_kernel(
        const float* __restrict__ deg, float* __restrict__ dis,
        const int* __restrict__ counts, int* __restrict__ offsets,
        int* __restrict__ cursor) {
    __shared__ int svals[2048];
    __shared__ int pa[256], pb[256];
    int t = threadIdx.x;
    for (int i = t; i < 2048; i += 256) svals[i] = (i < NN) ? counts[i] : 0;
    __syncthreads();
    int base = t * 8;
    int local[8];
    int s = 0;
#pragma unroll
    for (int j = 0; j < 8; ++j) { local[j] = s; s += svals[base + j]; }
    pa[t] = s;
    __syncthreads();
    int* psrc = pa; int* pdst = pb;
    for (int off = 1; off < 256; off <<= 1) {
        int v = psrc[t];
        if (t >= off) v += psrc[t - off];
        pdst[t] = v;
        __syncthreads();
        int* tmp = psrc; psrc = pdst; pdst = tmp;
    }
    int excl = psrc[t] - s;
#pragma unroll
    for (int j = 0; j < 8; ++j) {
        int i = base + j;
        if (i < NN) { int o = excl + local[j]; offsets[i] = o; cursor[i] = o; }
    }
    if (t == 255) offsets[NN] = psrc[255];
    for (int i = t; i < NN; i += 256) dis[i] = rsqrtf(deg[i] + 1.0f);
}

__global__ __launch_bounds__(256) void csr_fill_kernel(
        const int* __restrict__ row, const int* __restrict__ col,
        const float* __restrict__ ew, const float* __restrict__ dis,
        int* __restrict__ cursor, int* __restrict__ csr_src,
        float* __restrict__ csr_norm) {
    int e = blockIdx.x * 256 + threadIdx.x;
    if (e >= NE) return;
    int r = row[e], c = col[e];
    int pos = atomicAdd(&cursor[c], 1);
    csr_src[pos] = r;
    csr_norm[pos] = dis[r] * ew[e] * dis[c];
}

// ---------- gated conv via split-bf16 MFMA ----------
// Wave per 16-position M-tile (4 tiles/wave). Gates GEMM: A = x taps
// [16 x 64], B = gate weights [64 x 64] kept as register fragments.
// A-frag: A[m=lane&15][k=(lane>>4)*8+j]; B-frag: B[k=(lane>>4)*8+j][n=lane&15];
// C/D: col=lane&15, row=(lane>>4)*4+reg  (m89-verified).
// h written bf16 in (n, bt, c) layout for coalesced agg gathers.
__global__ __launch_bounds__(256) void conv_mfma_kernel(
        const float* __restrict__ x,
        const float* __restrict__ w1, const float* __restrict__ b1,
        const float* __restrict__ w2, const float* __restrict__ b2,
        unsigned short* __restrict__ h2) {
    int l = threadIdx.x & 63;
    int w = threadIdx.x >> 6;
    int col = l & 15, q = l >> 4;

    // B fragments [gate][dc-half][tap], hi/lo split. Loaded once per wave.
    short8 Whi[2][2][2], Wlo[2][2][2];
#pragma unroll
    for (int g = 0; g < 2; ++g) {
        const float* wp = g ? w2 : w1;
#pragma unroll
        for (int d = 0; d < 2; ++d)
#pragma unroll
        for (int tap = 0; tap < 2; ++tap) {
            short8 hi, lo;
#pragma unroll
            for (int j = 0; j < 8; ++j) {
                float wv = wp[(d * 16 + col) * 64 + (q * 8 + j) * 2 + tap];
                unsigned short h_, l_;
                split2(wv, h_, l_);
                hi[j] = (short)h_; lo[j] = (short)l_;
            }
            Whi[g][d][tap] = hi; Wlo[g][d][tap] = lo;
        }
    }
    float bias[2][2] = { { b1[col], b1[col + 16] }, { b2[col], b2[col + 16] } };

    for (int i = 0; i < 4; ++i) {
        int tile = blockIdx.x * 16 + w * 4 + i;
        int pos0 = tile * 16;
        int bt = pos0 / 2000;
        int n0 = pos0 - bt * 2000;
        int b_ = bt >> 5, t_ = bt & 31;
        const float* xa = x + (((b_ * T_IN + t_) * NN) + n0 + col) * 32 + q * 8;
        const float* xb = xa + 2 * NN * 32;   // dilation-2 tap
        float4 a01 = *(const float4*)xa;
        float4 a23 = *(const float4*)(xa + 4);
        float4 c01 = *(const float4*)xb;
        float4 c23 = *(const float4*)(xb + 4);
        short8 Ahi0, Alo0, Ahi1, Alo1;
        splitA(a01, a23, Ahi0, Alo0);
        splitA(c01, c23, Ahi1, Alo1);

        floatx4 acc[2][2];
#pragma unroll
        for (int g = 0; g < 2; ++g)
#pragma unroll
        for (int d = 0; d < 2; ++d) {
            float bv = bias[g][d];
            floatx4 a = { bv, bv, bv, bv };
            a = __builtin_amdgcn_mfma_f32_16x16x32_bf16(Ahi0, Whi[g][d][0], a, 0, 0, 0);
            a = __builtin_amdgcn_mfma_f32_16x16x32_bf16(Ahi1, Whi[g][d][1], a, 0, 0, 0);
            a = __builtin_amdgcn_mfma_f32_16x16x32_bf16(Alo0, Whi[g][d][0], a, 0, 0, 0);
            a = __builtin_amdgcn_mfma_f32_16x16x32_bf16(Alo1, Whi[g][d][1], a, 0, 0, 0);
            a = __builtin_amdgcn_mfma_f32_16x16x32_bf16(Ahi0, Wlo[g][d][0], a, 0, 0, 0);
            a = __builtin_amdgcn_mfma_f32_16x16x32_bf16(Ahi1, Wlo[g][d][1], a, 0, 0, 0);
            acc[g][d] = a;
        }

        // epilogue: h = tanh(g1) * sigmoid(g2); store bf16 to (n, bt, c)
#pragma unroll
        for (int d = 0; d < 2; ++d)
#pragma unroll
        for (int r = 0; r < 4; ++r) {
            float g1 = acc[0][d][r];
            float g2 = acc[1][d][r];
            float e2 = __expf(2.0f * g1);
            float th = (e2 - 1.0f) / (e2 + 1.0f);
            float sg = 1.0f / (1.0f + __expf(-g2));
            float h = th * sg;
            int n = n0 + q * 4 + r;
            h2[(n * NBT + bt) * 32 + d * 16 + col] = f2bf(h);
        }
    }
}

// ---------- aggregation: wave = (node, chunk of 8 bt) ----------
// Per edge: wave-uniform scalar src/norm + ONE fully-coalesced 512B bf16
// load of h2[src][chunk]. blockIdx%8 XCD swizzle: each XCD sees 2 chunks
// (2 MB h2 slice -> L2 resident). Writes s = aggregated h into d_out.
__global__ __launch_bounds__(256) void agg_kernel(
        const unsigned short* __restrict__ h2,
        const int* __restrict__ offsets, const int* __restrict__ csr_src,
        const float* __restrict__ csr_norm, const float* __restrict__ dis,
        float* __restrict__ s) {
    int l = threadIdx.x & 63;
    int wv = threadIdx.x >> 6;
    int b = blockIdx.x;
    int xcd = b & 7;
    int u = (b >> 3) * 4 + wv;            // 0..3999
    int cl = (u >= 2000) ? 1 : 0;
    int n = u - cl * 2000;
    int chunk = xcd * 2 + cl;             // 0..15
    const unsigned short* base = h2 + chunk * 256 + l * 4;

    float dn = dis[n];
    float w0 = dn * dn;                   // self-loop norm
    ushort4 sv = *(const ushort4*)(base + (size_t)n * 4096);
    float a0 = bf2f(sv.x) * w0, a1 = bf2f(sv.y) * w0;
    float a2 = bf2f(sv.z) * w0, a3 = bf2f(sv.w) * w0;

    int i = offsets[n], i1 = offsets[n + 1];
    for (; i + 4 <= i1; i += 4) {
        int sA = csr_src[i], sB = csr_src[i + 1], sC = csr_src[i + 2], sD = csr_src[i + 3];
        float nA = csr_norm[i], nB = csr_norm[i + 1], nC = csr_norm[i + 2], nD = csr_norm[i + 3];
        ushort4 vA = *(const ushort4*)(base + (size_t)sA * 4096);
        ushort4 vB = *(const ushort4*)(base + (size_t)sB * 4096);
        ushort4 vC = *(const ushort4*)(base + (size_t)sC * 4096);
        ushort4 vD = *(const ushort4*)(base + (size_t)sD * 4096);
        a0 += bf2f(vA.x) * nA; a1 += bf2f(vA.y) * nA; a2 += bf2f(vA.z) * nA; a3 += bf2f(vA.w) * nA;
        a0 += bf2f(vB.x) * nB; a1 += bf2f(vB.y) * nB; a2 += bf2f(vB.z) * nB; a3 += bf2f(vB.w) * nB;
        a0 += bf2f(vC.x) * nC; a1 += bf2f(vC.y) * nC; a2 += bf2f(vC.z) * nC; a3 += bf2f(vC.w) * nC;
        a0 += bf2f(vD.x) * nD; a1 += bf2f(vD.y) * nD; a2 += bf2f(vD.z) * nD; a3 += bf2f(vD.w) * nD;
    }
    for (; i < i1; ++i) {
        int sA = csr_src[i];
        float nA = csr_norm[i];
        ushort4 vA = *(const ushort4*)(base + (size_t)sA * 4096);
        a0 += bf2f(vA.x) * nA; a1 += bf2f(vA.y) * nA; a2 += bf2f(vA.z) * nA; a3 += bf2f(vA.w) * nA;
    }

    int btq = l >> 3, cq = l & 7;
    float4 o = make_float4(a0, a1, a2, a3);
    *(float4*)(s + (((size_t)(chunk * 8 + btq) * NN + n) << 5) + cq * 4) = o;
}

// ---------- gcn matmul, in-place on d_out: out = s * gcw + gcb ----------
__global__ __launch_bounds__(256) void gcn_mfma_kernel(
        float* __restrict__ s,
        const float* __restrict__ gw, const float* __restrict__ gb) {
    int l = threadIdx.x & 63, w = threadIdx.x >> 6;
    int col = l & 15, q = l >> 4;
    short8 Bhi[2], Blo[2];
#pragma unroll
    for (int d = 0; d < 2; ++d) {
        short8 hi, lo;
#pragma unroll
        for (int j = 0; j < 8; ++j) {
            float wv = gw[(q * 8 + j) * 32 + d * 16 + col];
            unsigned short h_, l_;
            split2(wv, h_, l_);
            hi[j] = (short)h_; lo[j] = (short)l_;
        }
        Bhi[d] = hi; Blo[d] = lo;
    }
    float gb0 = gb[col], gb1 = gb[col + 16];

    for (int i = 0; i < 4; ++i) {
        int tile = blockIdx.x * 16 + w * 4 + i;
        int pos0 = tile * 16;
        const float* ap = s + (size_t)(pos0 + col) * 32 + q * 8;
        float4 a01 = *(const float4*)ap;
        float4 a23 = *(const float4*)(ap + 4);
        short8 Ahi, Alo;
        splitA(a01, a23, Ahi, Alo);
        floatx4 z = { 0.f, 0.f, 0.f, 0.f };
        floatx4 acc0 = z, acc1 = z;
        acc0 = __builtin_amdgcn_mfma_f32_16x16x32_bf16(Ahi, Bhi[0], acc0, 0, 0, 0);
        acc0 = __builtin_amdgcn_mfma_f32_16x16x32_bf16(Alo, Bhi[0], acc0, 0, 0, 0);
        acc0 = __builtin_amdgcn_mfma_f32_16x16x32_bf16(Ahi, Blo[0], acc0, 0, 0, 0);
        acc1 = __builtin_amdgcn_mfma_f32_16x16x32_bf16(Ahi, Bhi[1], acc1, 0, 0, 0);
        acc1 = __builtin_amdgcn_mfma_f32_16x16x32_bf16(Alo, Bhi[1], acc1, 0, 0, 0);
        acc1 = __builtin_amdgcn_mfma_f32_16x16x32_bf16(Ahi, Blo[1], acc1, 0, 0, 0);
        // stores after all loads consumed (same-wave ordering is safe in-place)
#pragma unroll
        for (int r = 0; r < 4; ++r) {
            int p = pos0 + q * 4 + r;
            s[(size_t)p * 32 + col]      = acc0[r] + gb0;
            s[(size_t)p * 32 + col + 16] = acc1[r] + gb1;
        }
    }
}

extern "C" void kernel_launch(void* const* d_in, const int* in_sizes, int n_in,
                              void* d_out, int out_size, void* d_ws, size_t ws_size,
                              hipStream_t stream) {
    const float* x   = (const float*)d_in[0];
    const int*   ei  = (const int*)d_in[1];
    const float* ew  = (const float*)d_in[2];
    const float* g1w = (const float*)d_in[3];
    const float* g1b = (const float*)d_in[4];
    const float* g2w = (const float*)d_in[5];
    const float* g2b = (const float*)d_in[6];
    const float* gcw = (const float*)d_in[7];
    const float* gcb = (const float*)d_in[8];
    float* out = (float*)d_out;

    float* wsf      = (float*)d_ws;
    float* deg      = wsf;
    float* dis      = wsf + 2048;
    int*   counts   = (int*)(wsf + 4096);
    int*   offsets  = (int*)(wsf + 6144);
    int*   cursor   = (int*)(wsf + 8192);
    int*   csr_src  = (int*)(wsf + 10240);
    float* csr_norm = wsf + 51200;
    unsigned short* h2 = (unsigned short*)(wsf + 92160);

    const int* row = ei;
    const int* col = ei + NE;

    hipLaunchKernelGGL(zero_kernel, dim3(24), dim3(256), 0, stream, wsf);
    hipLaunchKernelGGL(deg_count_kernel, dim3((NE + 255) / 256), dim3(256), 0, stream,
                       col, ew, deg, counts);
    hipLaunchKernelGGL(scan_kernel, dim3(1), dim3(256), 0, stream,
                       deg, dis, counts, offsets, cursor);
    hipLaunchKernelGGL(csr_fill_kernel, dim3((NE + 255) / 256), dim3(256), 0, stream,
                       row, col, ew, dis, cursor, csr_src, csr_norm);
    hipLaunchKernelGGL(conv_mfma_kernel, dim3(1000), dim3(256), 0, stream,
                       x, g1w, g1b, g2w, g2b, h2);
    hipLaunchKernelGGL(agg_kernel, dim3(8000), dim3(256), 0, stream,
                       h2, offsets, csr_src, csr_norm, dis, out);
    hipLaunchKernelGGL(gcn_mfma_kernel, dim3(1000), dim3(256), 0, stream,
                       out, gcw, gcb);
}